// Round 1
// baseline (1343.919 us; speedup 1.0000x reference)
//
#include <hip/hip_runtime.h>

// GMSA: proj_in(1x1 conv + BN, fused) -> 3x shifted-window self-attn -> concat -> proj_out
// fp32 throughout. d_out = [y (8,60,288,288), atn4, atn8, atn12] flat fp32.

constexpr int HH = 288;
constexpr int HW = 288 * 288;
constexpr long long YBUF_ELEMS = 8LL * 60 * HW;          // 39,813,120
constexpr long long ATN0_OFF = YBUF_ELEMS;               // ws=4
constexpr long long ATN1_OFF = ATN0_OFF + 41472LL * 256; // ws=8  (50,429,952)
constexpr long long ATN2_OFF = ATN1_OFF + 10368LL * 4096;// ws=12 (92,897,280)

// ---------------- prep: fold BN into W_in/b_in ----------------
__global__ void prep_kernel(const float* __restrict__ W_in, const float* __restrict__ b_in,
                            const float* __restrict__ gamma, const float* __restrict__ beta,
                            const float* __restrict__ mean, const float* __restrict__ var,
                            float* __restrict__ Wp, float* __restrict__ bp) {
    int o = threadIdx.x;
    if (o < 120) {
        float inv = gamma[o] / sqrtf(var[o] + 1e-5f);
        for (int c = 0; c < 60; ++c) Wp[o * 60 + c] = W_in[o * 60 + c] * inv;
        bp[o] = b_in[o] * inv + beta[o] - mean[o] * inv;
    }
}

// ---------------- branch kernel ----------------
// TPR==1: thread = (window-in-block, row). TPR==4 (ws=12): 4 lanes per row, 36 cols each.
template <int WS, int P, int NWIN, int BLOCK, int TPR, int BRANCH>
__launch_bounds__(BLOCK)
__global__ void branch_kernel(const float* __restrict__ x,
                              const float* __restrict__ Wp,
                              const float* __restrict__ bp,
                              float* __restrict__ ybuf,
                              float* __restrict__ atn) {
    constexpr int SH = WS / 2;
    constexpr int NWND = 288 / WS;
    constexpr int QVS = P * 20 + 8;   // padded per-window LDS stride (floats)
    constexpr int COFF = BRANCH * 40;
    constexpr int CPT = P / TPR;      // columns per thread

    __shared__ float q_lds[NWIN * QVS];
    __shared__ float v_lds[NWIN * QVS];
    __shared__ float xs[(TPR > 1) ? (P * 61) : 1];

    const int tid = threadIdx.x;
    const int w0 = blockIdx.x * NWIN;

    // ---------- projection phase ----------
    if constexpr (TPR == 1) {
        const int widx = tid / P;
        const int pix  = tid % P;
        const int w    = w0 + widx;
        const int b    = w / (NWND * NWND);
        const int rem  = w % (NWND * NWND);
        const int wi   = rem / NWND;
        const int wj   = rem % NWND;
        const int gh   = (wi * WS + pix / WS + SH) % 288;
        const int gw   = (wj * WS + pix % WS + SH) % 288;
        float xv[60];
        const float* xb = x + (long long)b * 60 * HW + gh * 288 + gw;
        #pragma unroll
        for (int c = 0; c < 60; ++c) xv[c] = xb[(long long)c * HW];
        #pragma unroll
        for (int oc = 0; oc < 40; ++oc) {
            float acc = bp[COFF + oc];
            const float* wr = Wp + (COFF + oc) * 60;
            #pragma unroll
            for (int c = 0; c < 60; ++c) acc = fmaf(wr[c], xv[c], acc);
            if (oc < 20) q_lds[widx * QVS + pix * 20 + oc] = acc;
            else         v_lds[widx * QVS + pix * 20 + (oc - 20)] = acc;
        }
    } else {
        // ws=12: stage x window [P][60] into LDS (stride 61), then 4-way channel-split proj
        const int w   = w0;
        const int b   = w / (NWND * NWND);
        const int rem = w % (NWND * NWND);
        const int wi  = rem / NWND;
        const int wj  = rem % NWND;
        for (int idx = tid; idx < 60 * P; idx += BLOCK) {
            int cc = idx / P;
            int pix = idx % P;
            int gh = (wi * WS + pix / WS + SH) % 288;
            int gw = (wj * WS + pix % WS + SH) % 288;
            xs[pix * 61 + cc] = x[((long long)b * 60 + cc) * HW + gh * 288 + gw];
        }
        __syncthreads();
        const int pix = tid >> 2;
        const int qt  = tid & 3;
        const float* xr = xs + pix * 61;
        #pragma unroll
        for (int i = 0; i < 10; ++i) {
            int oc = qt * 10 + i;
            float acc = bp[COFF + oc];
            const float* wr = Wp + (COFF + oc) * 60;
            #pragma unroll
            for (int c = 0; c < 60; ++c) acc = fmaf(wr[c], xr[c], acc);
            if (oc < 20) q_lds[pix * 20 + oc] = acc;
            else         v_lds[pix * 20 + (oc - 20)] = acc;
        }
    }
    __syncthreads();

    // ---------- attention phase ----------
    const int widx = (TPR == 1) ? (tid / P) : 0;
    const int r    = (TPR == 1) ? (tid % P) : (tid >> 2);
    const int sub  = (TPR == 1) ? 0 : (tid & 3);
    const int w    = w0 + widx;
    const int b    = w / (NWND * NWND);
    const int rem  = w % (NWND * NWND);
    const int wi   = rem / NWND;
    const int wj   = rem % NWND;

    const float* qbase = q_lds + widx * QVS;
    const float* vbase = v_lds + widx * QVS;

    float qr[20];
    #pragma unroll
    for (int cc = 0; cc < 5; ++cc) {
        float4 t = *reinterpret_cast<const float4*>(qbase + r * 20 + cc * 4);
        qr[cc*4+0] = t.x; qr[cc*4+1] = t.y; qr[cc*4+2] = t.z; qr[cc*4+3] = t.w;
    }

    float s[CPT];
    #pragma unroll
    for (int k = 0; k < CPT; ++k) {
        const float* qj = qbase + (sub * CPT + k) * 20;
        float4 a0 = *reinterpret_cast<const float4*>(qj + 0);
        float4 a1 = *reinterpret_cast<const float4*>(qj + 4);
        float4 a2 = *reinterpret_cast<const float4*>(qj + 8);
        float4 a3 = *reinterpret_cast<const float4*>(qj + 12);
        float4 a4 = *reinterpret_cast<const float4*>(qj + 16);
        float acc = 0.f;
        acc = fmaf(qr[0],  a0.x, acc); acc = fmaf(qr[1],  a0.y, acc);
        acc = fmaf(qr[2],  a0.z, acc); acc = fmaf(qr[3],  a0.w, acc);
        acc = fmaf(qr[4],  a1.x, acc); acc = fmaf(qr[5],  a1.y, acc);
        acc = fmaf(qr[6],  a1.z, acc); acc = fmaf(qr[7],  a1.w, acc);
        acc = fmaf(qr[8],  a2.x, acc); acc = fmaf(qr[9],  a2.y, acc);
        acc = fmaf(qr[10], a2.z, acc); acc = fmaf(qr[11], a2.w, acc);
        acc = fmaf(qr[12], a3.x, acc); acc = fmaf(qr[13], a3.y, acc);
        acc = fmaf(qr[14], a3.z, acc); acc = fmaf(qr[15], a3.w, acc);
        acc = fmaf(qr[16], a4.x, acc); acc = fmaf(qr[17], a4.y, acc);
        acc = fmaf(qr[18], a4.z, acc); acc = fmaf(qr[19], a4.w, acc);
        s[k] = acc;
    }

    float m = s[0];
    #pragma unroll
    for (int k = 1; k < CPT; ++k) m = fmaxf(m, s[k]);
    if constexpr (TPR > 1) {
        m = fmaxf(m, __shfl_xor(m, 1, TPR));
        m = fmaxf(m, __shfl_xor(m, 2, TPR));
    }
    float sum = 0.f;
    #pragma unroll
    for (int k = 0; k < CPT; ++k) { s[k] = __expf(s[k] - m); sum += s[k]; }
    if constexpr (TPR > 1) {
        sum += __shfl_xor(sum, 1, TPR);
        sum += __shfl_xor(sum, 2, TPR);
    }
    const float inv = 1.0f / sum;
    #pragma unroll
    for (int k = 0; k < CPT; ++k) s[k] *= inv;

    // write attention row chunk (coalesced float4)
    float* arow = atn + ((long long)w * P + r) * P + sub * CPT;
    #pragma unroll
    for (int k = 0; k < CPT; k += 4) {
        *reinterpret_cast<float4*>(arow + k) = make_float4(s[k], s[k+1], s[k+2], s[k+3]);
    }

    // y = atn @ v
    float acc[20];
    #pragma unroll
    for (int c = 0; c < 20; ++c) acc[c] = 0.f;
    #pragma unroll
    for (int k = 0; k < CPT; ++k) {
        const float* vj = vbase + (sub * CPT + k) * 20;
        float a = s[k];
        float4 b0 = *reinterpret_cast<const float4*>(vj + 0);
        float4 b1 = *reinterpret_cast<const float4*>(vj + 4);
        float4 b2 = *reinterpret_cast<const float4*>(vj + 8);
        float4 b3 = *reinterpret_cast<const float4*>(vj + 12);
        float4 b4 = *reinterpret_cast<const float4*>(vj + 16);
        acc[0]  = fmaf(a, b0.x, acc[0]);  acc[1]  = fmaf(a, b0.y, acc[1]);
        acc[2]  = fmaf(a, b0.z, acc[2]);  acc[3]  = fmaf(a, b0.w, acc[3]);
        acc[4]  = fmaf(a, b1.x, acc[4]);  acc[5]  = fmaf(a, b1.y, acc[5]);
        acc[6]  = fmaf(a, b1.z, acc[6]);  acc[7]  = fmaf(a, b1.w, acc[7]);
        acc[8]  = fmaf(a, b2.x, acc[8]);  acc[9]  = fmaf(a, b2.y, acc[9]);
        acc[10] = fmaf(a, b2.z, acc[10]); acc[11] = fmaf(a, b2.w, acc[11]);
        acc[12] = fmaf(a, b3.x, acc[12]); acc[13] = fmaf(a, b3.y, acc[13]);
        acc[14] = fmaf(a, b3.z, acc[14]); acc[15] = fmaf(a, b3.w, acc[15]);
        acc[16] = fmaf(a, b4.x, acc[16]); acc[17] = fmaf(a, b4.y, acc[17]);
        acc[18] = fmaf(a, b4.z, acc[18]); acc[19] = fmaf(a, b4.w, acc[19]);
    }
    if constexpr (TPR > 1) {
        #pragma unroll
        for (int c = 0; c < 20; ++c) {
            acc[c] += __shfl_xor(acc[c], 1, TPR);
            acc[c] += __shfl_xor(acc[c], 2, TPR);
        }
    }

    const int oh = (wi * WS + r / WS + SH) % 288;
    const int ow = (wj * WS + r % WS + SH) % 288;
    if constexpr (TPR == 1) {
        float* yb = ybuf + ((long long)b * 60 + BRANCH * 20) * HW + oh * 288 + ow;
        #pragma unroll
        for (int c = 0; c < 20; ++c) yb[(long long)c * HW] = acc[c];
    } else {
        if (sub == 0) {
            float* yb = ybuf + ((long long)b * 60 + BRANCH * 20) * HW + oh * 288 + ow;
            #pragma unroll
            for (int c = 0; c < 20; ++c) yb[(long long)c * HW] = acc[c];
        }
    }
}

// ---------------- proj_out ----------------
__global__ __launch_bounds__(256) void proj_out_kernel(const float* __restrict__ ybuf,
                                                       const float* __restrict__ Wout,
                                                       const float* __restrict__ bout,
                                                       float* __restrict__ out) {
    const long long pixel = (long long)blockIdx.x * 256 + threadIdx.x; // < 8*HW
    const int b  = (int)(pixel / HW);
    const int hw = (int)(pixel % HW);
    float yv[60];
    const float* yb = ybuf + (long long)b * 60 * HW + hw;
    #pragma unroll
    for (int c = 0; c < 60; ++c) yv[c] = yb[(long long)c * HW];
    #pragma unroll 4
    for (int o = 0; o < 60; ++o) {
        float acc = bout[o];
        const float* wr = Wout + o * 60;
        #pragma unroll
        for (int c = 0; c < 60; ++c) acc = fmaf(wr[c], yv[c], acc);
        out[((long long)b * 60 + o) * HW + hw] = acc;
    }
}

extern "C" void kernel_launch(void* const* d_in, const int* in_sizes, int n_in,
                              void* d_out, int out_size, void* d_ws, size_t ws_size,
                              hipStream_t stream) {
    const float* x     = (const float*)d_in[0];
    const float* W_in  = (const float*)d_in[1];
    const float* b_in  = (const float*)d_in[2];
    const float* gamma = (const float*)d_in[3];
    const float* beta  = (const float*)d_in[4];
    const float* mean  = (const float*)d_in[5];
    const float* var   = (const float*)d_in[6];
    const float* Wout  = (const float*)d_in[7];
    const float* bout  = (const float*)d_in[8];
    float* out = (float*)d_out;

    float* wsf  = (float*)d_ws;
    float* ybuf = wsf;
    float* Wp   = wsf + YBUF_ELEMS;
    float* bp   = Wp + 7200;

    prep_kernel<<<1, 128, 0, stream>>>(W_in, b_in, gamma, beta, mean, var, Wp, bp);

    branch_kernel<4, 16, 16, 256, 1, 0><<<2592, 256, 0, stream>>>(x, Wp, bp, ybuf, out + ATN0_OFF);
    branch_kernel<8, 64, 4, 256, 1, 1><<<2592, 256, 0, stream>>>(x, Wp, bp, ybuf, out + ATN1_OFF);
    branch_kernel<12, 144, 1, 576, 4, 2><<<4608, 576, 0, stream>>>(x, Wp, bp, ybuf, out + ATN2_OFF);

    proj_out_kernel<<<2592, 256, 0, stream>>>(ybuf, Wout, bout, out);
}